// Round 15
// baseline (89.681 us; speedup 1.0000x reference)
//
#include <hip/hip_runtime.h>

// 8-connected CCL on a 2048x2048 mask (prob > 0.5).
// Output int32: (component min flat index)+1 for fg, 0 for bg.
//
//   1. k_local   : per 128x64 tile (32KB LDS, 2 blocks/CU), ballot/run-based
//                  union-find (round-12 proven form).
//   2. k_seam    : cross-tile unions, 128-px chunks, run-dedup'd; gunite =
//                  PURE-READ find + atomicMin attach. No path-halving: the
//                  forest enters depth<=1 and only ~25K attaches deepen it,
//                  while each halving RMW invalidates the hot chain lines in
//                  every other CU's L1 (the r11 win was exactly making those
//                  reads L1-cheap). Reads may be stale -- attach catches it.
//   3. k_compress: READ-ONLY chase, int4-vectorized (4 px/thread) with
//                  chase-sharing between equal neighbor labels.

#define H 2048
#define W 2048
#define NPIX (H * W)
#define TSX 128           // tile width  (mask = 2 x u64)
#define TSY 64            // tile height
#define RPT 4             // rows per thread = TSY / 16

// sidecar layout (int32 units): seam s in 0..14 at column x=128(s+1):
//   A side (col x-1): wsv[s*4096 + y]   B side (col x): wsv[s*4096+2048+y]
// 15*4096 ints = 240 KB; every slot rewritten every call (bg writes 0).

// ---------- global union-find, 1-based parents, PURE-READ find ----------
// Plain L1 loads, no halving writes. SAFE:
//  - indices strictly decrease along a chain -> walk terminates;
//  - a stale parent is a past ancestor (parents only decrease, same
//    component), so the walk lands on a node that WAS a root;
//  - staleness is caught at attach: atomicMin is coherent; if it overwrote
//    a real parent c (old != b+1), we CONTINUE WITH c, re-uniting through
//    it, which repairs the severed b~c relation (Komura retry invariant).
__device__ __forceinline__ int gfind(const int* __restrict__ L, int a) {
    int n = L[a];
    while (n != a + 1) { a = n - 1; n = L[a]; }
    return a;
}

__device__ __forceinline__ void gunite(int* __restrict__ L, int a, int b) {
    while (true) {
        a = gfind(L, a);
        b = gfind(L, b);
        if (a == b) return;
        if (a > b) { int t = a; a = b; b = t; }
        int old = atomicMin(&L[b], a + 1);
        if (old == b + 1) return;   // attached larger root under smaller
        b = old - 1;                // raced/stale; continue from observed
    }                               // parent (repairs any severed link)
}

// ---------- local (LDS) union-find, 0-based, -1 = background ----------
__device__ __forceinline__ int lfind(volatile int* L, int a) {
    int n = L[a];
    while (n != a) { a = n; n = L[a]; }
    return a;
}

// find with atomicMin path-halving (safe under concurrent unions: parents
// only decrease and remain in-component). LDS atomics are cheap -- halving
// stays ON locally (it kept r7->r8 fast; only the GLOBAL halving hurt).
__device__ __forceinline__ int lfind_h(int* L, int a) {
    volatile int* Lv = L;
    int n = Lv[a];
    while (n != a) {
        int g = Lv[n];
        if (g != n) atomicMin(&L[a], g);
        a = n; n = g;
    }
    return a;
}

__device__ __forceinline__ void lunite(int* L, int a, int b) {
    while (true) {
        a = lfind_h(L, a);
        b = lfind_h(L, b);
        if (a == b) return;
        if (a > b) { int t = a; a = b; b = t; }
        int old = atomicMin(&L[b], a);
        if (old == b) return;
        b = old;
    }
}

// run start (smallest s<=p with bits s..p all set; requires bit p set)
__device__ __forceinline__ int run_start64(unsigned long long m, int p) {
    if (p == 0) return 0;
    unsigned long long below = m << (64 - p);   // bit p-1 -> bit 63
    return p - __builtin_clzll(~below);         // minus count of leading ones
}

__device__ __forceinline__ int run_start128(unsigned long long u0,
                                            unsigned long long u1, int p) {
    if (p >= 64) {
        int s = run_start64(u1, p - 64) + 64;
        if (s == 64 && (u0 >> 63)) s = run_start64(u0, 63);  // continues left
        return s;
    }
    return run_start64(u0, p);
}

__device__ __forceinline__ int getbit128(unsigned long long u0,
                                         unsigned long long u1, int p) {
    if (p < 0 || p > 127) return 0;
    return (int)((p < 64 ? (u0 >> p) : (u1 >> (p - 64))) & 1ull);
}

__global__ __launch_bounds__(1024)
void k_local(const float* __restrict__ prob, int* __restrict__ lab,
             int* __restrict__ wsv) {
    __shared__ int slab[TSY * TSX];                       // 32 KB
    __shared__ unsigned long long mrow0[TSY], mrow1[TSY]; // 1 KB mask table
    const int x0 = blockIdx.x * TSX, y0 = blockIdx.y * TSY;
    const int lx = threadIdx.x;                 // 0..63 == lane
    const int ty = threadIdx.y;                 // 0..15

    unsigned long long rM0[RPT], rM1[RPT];
    int sA[RPT], sB[RPT];                       // run starts, register-cached

    // init: two ballots per row; label := row-global run start (kills all
    // horizontal unions, incl. across the 64-lane segment boundary)
    #pragma unroll
    for (int k = 0; k < RPT; ++k) {
        int ly = ty * RPT + k;
        const float* rowp = prob + (long)(y0 + ly) * W + x0;
        bool f0 = rowp[lx] > 0.5f;
        bool f1 = rowp[64 + lx] > 0.5f;
        unsigned long long m0 = __ballot(f0);
        unsigned long long m1 = __ballot(f1);
        rM0[k] = m0; rM1[k] = m1;
        int s0 = f0 ? run_start128(m0, m1, lx) : lx;
        int s1 = f1 ? run_start128(m0, m1, 64 + lx) : 64 + lx;
        sA[k] = s0; sB[k] = s1;
        slab[ly * TSX + lx]      = f0 ? ly * TSX + s0 : -1;
        slab[ly * TSX + 64 + lx] = f1 ? ly * TSX + s1 : -1;
        if (lx == 0) { mrow0[ly] = m0; mrow1[ly] = m1; }
    }
    __syncthreads();

    // vertical unions, once per (my-run, upper-segment) overlap.
    // Control uses ONLY register-cached / mask-table values (slab roots
    // mutate under concurrent lunite -- round-4 lesson).
    #pragma unroll
    for (int k = 0; k < RPT; ++k) {
        int ly = ty * RPT + k;
        if (ly == 0) continue;
        unsigned long long u0 = mrow0[ly - 1], u1 = mrow1[ly - 1];
        unsigned long long m0 = rM0[k], m1 = rM1[k];
        #pragma unroll
        for (int h = 0; h < 2; ++h) {
            int pos = h * 64 + lx;
            if (!getbit128(m0, m1, pos)) continue;
            int s = h ? sB[k] : sA[k];
            int mylab = ly * TSX + s;
            if (getbit128(u0, u1, pos)) {
                if (pos == s || !getbit128(u0, u1, pos - 1))
                    lunite(slab, mylab, (ly - 1) * TSX + run_start128(u0, u1, pos));
            } else {
                if (pos == s && getbit128(u0, u1, pos - 1))
                    lunite(slab, mylab, (ly - 1) * TSX + run_start128(u0, u1, pos - 1));
                bool isEnd = (pos == 127) || !getbit128(m0, m1, pos + 1);
                if (isEnd && getbit128(u0, u1, pos + 1))
                    lunite(slab, mylab, (ly - 1) * TSX + (pos + 1));
            }
        }
    }
    __syncthreads();

    // flatten step a: pre-flatten RUN-START entries only. Tree is static
    // now; plain stores write true roots.
    #pragma unroll
    for (int k = 0; k < RPT; ++k) {
        int ly = ty * RPT + k;
        unsigned long long m0 = rM0[k], m1 = rM1[k];
        if (((m0 >> lx) & 1) && sA[k] == lx) {
            int li = ly * TSX + lx;
            slab[li] = lfind(slab, li);
        }
        if (((m1 >> lx) & 1) && sB[k] == 64 + lx) {
            int li = ly * TSX + 64 + lx;
            slab[li] = lfind(slab, li);
        }
    }
    __syncthreads();

    // flatten step b: one LDS read at the register-cached run start
    // (same-run lanes broadcast). Edge labels also go to the seam sidecar.
    #pragma unroll
    for (int k = 0; k < RPT; ++k) {
        int ly = ty * RPT + k;
        unsigned long long m0 = rM0[k], m1 = rM1[k];
        int out0 = 0, out1 = 0;
        if ((m0 >> lx) & 1) {
            int r = slab[ly * TSX + sA[k]];
            out0 = (y0 + (r >> 7)) * W + (x0 + (r & 127)) + 1;
        }
        if ((m1 >> lx) & 1) {
            int r = slab[ly * TSX + sB[k]];
            out1 = (y0 + (r >> 7)) * W + (x0 + (r & 127)) + 1;
        }
        lab[(long)(y0 + ly) * W + x0 + lx]      = out0;
        lab[(long)(y0 + ly) * W + x0 + 64 + lx] = out1;
        if (lx == 0 && blockIdx.x > 0)            // left edge -> B side
            wsv[(blockIdx.x - 1) * 4096 + 2048 + (y0 + ly)] = out0;
        if (lx == 63 && blockIdx.x < 15)          // right edge -> A side
            wsv[blockIdx.x * 4096 + (y0 + ly)] = out1;
    }
}

// Cross-tile seam merge. 736 wave-tasks: 240 vertical (sidecar) + 496
// horizontal (contiguous lab rows). One gunite per (B-run, A-run) overlap
// segment (covered / left-touch / right-touch). Chunks crossing
// perpendicular tile boundaries stay correct by transitivity.
__global__ __launch_bounds__(256)
void k_seam(int* __restrict__ lab, const int* __restrict__ wsv) {
    int gtid = blockIdx.x * blockDim.x + threadIdx.x;
    int task = gtid >> 6;
    int lane = gtid & 63;
    bool vertical = task < 240;
    int t = vertical ? task : task - 240;
    int seam = t >> 4, chunk = t & 15;

    const int* aPtr;
    const int* bPtr;
    int y_h = 0, xb_h = 0;
    if (vertical) {
        int ybase = chunk << 7;            // 128-row chunk
        aPtr = wsv + seam * 4096 + ybase;          // col x-1 labels
        bPtr = wsv + seam * 4096 + 2048 + ybase;   // col x   labels
    } else {
        y_h = (seam + 1) << 6;             // seam row (every 64)
        xb_h = chunk << 7;
        bPtr = lab + (long)y_h * W + xb_h;
        aPtr = bPtr - W;
    }
    int B0 = bPtr[lane], B1 = bPtr[64 + lane];
    int A0 = aPtr[lane], A1 = aPtr[64 + lane];

    unsigned long long m0 = __ballot(B0 != 0), m1 = __ballot(B1 != 0);
    unsigned long long u0 = __ballot(A0 != 0), u1 = __ballot(A1 != 0);

    #pragma unroll
    for (int h = 0; h < 2; ++h) {
        int pos = (h << 6) | lane;
        if (!getbit128(m0, m1, pos)) continue;
        int myB = h ? B1 : B0;
        int s = run_start128(m0, m1, pos);
        if (getbit128(u0, u1, pos)) {
            if (pos == s || !getbit128(u0, u1, pos - 1)) {
                int tgt = h ? A1 : A0;
                gunite(lab, myB - 1, tgt - 1);
            }
        } else {
            if (pos == s && pos > 0 && getbit128(u0, u1, pos - 1)) {
                gunite(lab, myB - 1, aPtr[pos - 1] - 1);
            }
            bool isEnd = (pos == 127) || !getbit128(m0, m1, pos + 1);
            if (isEnd && pos < 127 && getbit128(u0, u1, pos + 1)) {
                gunite(lab, myB - 1, aPtr[pos + 1] - 1);
            }
        }
    }

    // corner diagonal links (horizontal chunks only, edge lanes)
    if (!vertical && lane == 0) {
        if (xb_h > 0 && (m0 & 1) && !(u0 & 1)) {           // NW corner
            int tgt = lab[(long)(y_h - 1) * W + xb_h - 1];
            if (tgt) gunite(lab, B0 - 1, tgt - 1);
        }
        if (xb_h + 128 < W && ((m1 >> 63) & 1) && !((u1 >> 63) & 1)) {  // NE
            int tgt = lab[(long)(y_h - 1) * W + xb_h + 128];
            if (tgt) {
                int b127 = lab[(long)y_h * W + xb_h + 127];
                gunite(lab, b127 - 1, tgt - 1);
            }
        }
    }
}

// READ-ONLY compress, int4-vectorized: 4 px/thread with chase-sharing
// (consecutive labels usually identical -- same run). Tree is static here;
// no halving writes. Concurrent readers of our 16B store see old-or-new
// per 4B element, both valid ancestors.
__device__ __forceinline__ int resolve(const int* __restrict__ L, int v) {
    if (v == 0) return 0;
    int a = v - 1;
    int n = L[a];
    while (n != a + 1) { a = n - 1; n = L[a]; }
    return a + 1;
}

__global__ __launch_bounds__(256)
void k_compress(int* __restrict__ lab) {
    int q = blockIdx.x * blockDim.x + threadIdx.x;  // quad index
    int4 v = ((const int4*)lab)[q];
    int o0 = resolve(lab, v.x);
    int o1 = (v.y == v.x) ? o0 : resolve(lab, v.y);
    int o2 = (v.z == v.y) ? o1 : resolve(lab, v.z);
    int o3 = (v.w == v.z) ? o2 : resolve(lab, v.w);
    if (o0 != v.x || o1 != v.y || o2 != v.z || o3 != v.w)
        ((int4*)lab)[q] = make_int4(o0, o1, o2, o3);
}

extern "C" void kernel_launch(void* const* d_in, const int* in_sizes, int n_in,
                              void* d_out, int out_size, void* d_ws, size_t ws_size,
                              hipStream_t stream) {
    const float* prob = (const float*)d_in[0];
    int* lab = (int*)d_out;
    int* wsv = (int*)d_ws;               // 240 KB sidecar

    dim3 lgrid(W / TSX, H / TSY);        // 16 x 32 = 512 blocks (2/CU)
    dim3 lblock(64, 16);                 // 1024 threads, 16 waves
    k_local<<<lgrid, lblock, 0, stream>>>(prob, lab, wsv);

    // 736 wave-tasks * 64 lanes = 47104 threads = 184 blocks exactly
    k_seam<<<184, 256, 0, stream>>>(lab, wsv);

    k_compress<<<NPIX / 4 / 256, 256, 0, stream>>>(lab);
}

// Round 16
// 73.651 us; speedup vs baseline: 1.2176x; 1.2176x over previous
//
#include <hip/hip_runtime.h>

// 8-connected CCL on a 2048x2048 mask (prob > 0.5).
// Output int32: (component min flat index)+1 for fg, 0 for bg.
//
// ROUND-14 CONFIGURATION (measured best, 73.8 us). Family bracketing:
//   gunite = halving-find + attach, PLAIN L1 loads   -> ~30 us (r11/r14) BEST
//   gunite = halving-find + attach, agent-scope loads-> ~52 us (r8)
//   gunite = pure-read find + attach (no halving)    -> ~45 us (r15)
//   gunite = atomicMin walk (no find)                -> ~149 us (r9)
// Lesson: wave latency ~ longest-chain hops x mem latency; halving bounds
// chain growth, plain loads keep hops in L1, attach-retry repairs staleness.
//
//   1. k_local   : per 128x64 tile (32KB LDS, 2 blocks/CU), ballot/run-based
//                  union-find (round-12 proven form -- NO seeded parents:
//                  seeding built deep chains, 3x regression r13).
//   2. k_seam    : cross-tile unions, 128-px chunks, run-dedup'd;
//                  vertical seams read a coalesced d_ws sidecar.
//   3. k_compress: READ-ONLY chase, int4-vectorized, chase-sharing.

#define H 2048
#define W 2048
#define NPIX (H * W)
#define TSX 128           // tile width  (mask = 2 x u64)
#define TSY 64            // tile height
#define RPT 4             // rows per thread = TSY / 16

// sidecar layout (int32 units): seam s in 0..14 at column x=128(s+1):
//   A side (col x-1): wsv[s*4096 + y]   B side (col x): wsv[s*4096+2048+y]
// 15*4096 ints = 240 KB; every slot rewritten every call (bg writes 0).

// ---------- global union-find, 1-based parents, path-halving find ----------
// PLAIN loads: L1 may serve stale parents. SAFE: stale parent = past
// ancestor (same component; parents only decrease); halving atomicMin only
// lowers toward a valid ancestor; stale roots are caught at attach (atomics
// coherent) and the failed-attach continuation repairs any severed link.
__device__ __forceinline__ int gfind(int* __restrict__ L, int a) {
    int n = L[a];
    while (n != a + 1) {
        int p = n - 1;
        int g = L[p];                     // grandparent+1 (possibly stale)
        if (g != n) atomicMin(&L[a], g);  // MUST be atomicMin (see above)
        a = p; n = g;
    }
    return a;
}

__device__ __forceinline__ void gunite(int* __restrict__ L, int a, int b) {
    while (true) {
        a = gfind(L, a);
        b = gfind(L, b);
        if (a == b) return;
        if (a > b) { int t = a; a = b; b = t; }
        int old = atomicMin(&L[b], a + 1);
        if (old == b + 1) return;   // attached larger root under smaller
        b = old - 1;                // raced/stale; continue from observed
    }                               // parent (repairs any severed link)
}

// ---------- local (LDS) union-find, 0-based, -1 = background ----------
__device__ __forceinline__ int lfind(volatile int* L, int a) {
    int n = L[a];
    while (n != a) { a = n; n = L[a]; }
    return a;
}

// find with atomicMin path-halving (safe under concurrent unions: parents
// only decrease and remain in-component)
__device__ __forceinline__ int lfind_h(int* L, int a) {
    volatile int* Lv = L;
    int n = Lv[a];
    while (n != a) {
        int g = Lv[n];
        if (g != n) atomicMin(&L[a], g);
        a = n; n = g;
    }
    return a;
}

__device__ __forceinline__ void lunite(int* L, int a, int b) {
    while (true) {
        a = lfind_h(L, a);
        b = lfind_h(L, b);
        if (a == b) return;
        if (a > b) { int t = a; a = b; b = t; }
        int old = atomicMin(&L[b], a);
        if (old == b) return;
        b = old;
    }
}

// run start (smallest s<=p with bits s..p all set; requires bit p set)
__device__ __forceinline__ int run_start64(unsigned long long m, int p) {
    if (p == 0) return 0;
    unsigned long long below = m << (64 - p);   // bit p-1 -> bit 63
    return p - __builtin_clzll(~below);         // minus count of leading ones
}

__device__ __forceinline__ int run_start128(unsigned long long u0,
                                            unsigned long long u1, int p) {
    if (p >= 64) {
        int s = run_start64(u1, p - 64) + 64;
        if (s == 64 && (u0 >> 63)) s = run_start64(u0, 63);  // continues left
        return s;
    }
    return run_start64(u0, p);
}

__device__ __forceinline__ int getbit128(unsigned long long u0,
                                         unsigned long long u1, int p) {
    if (p < 0 || p > 127) return 0;
    return (int)((p < 64 ? (u0 >> p) : (u1 >> (p - 64))) & 1ull);
}

__global__ __launch_bounds__(1024)
void k_local(const float* __restrict__ prob, int* __restrict__ lab,
             int* __restrict__ wsv) {
    __shared__ int slab[TSY * TSX];                       // 32 KB
    __shared__ unsigned long long mrow0[TSY], mrow1[TSY]; // 1 KB mask table
    const int x0 = blockIdx.x * TSX, y0 = blockIdx.y * TSY;
    const int lx = threadIdx.x;                 // 0..63 == lane
    const int ty = threadIdx.y;                 // 0..15

    unsigned long long rM0[RPT], rM1[RPT];
    int sA[RPT], sB[RPT];                       // run starts, register-cached

    // init: two ballots per row; label := row-global run start (kills all
    // horizontal unions, incl. across the 64-lane segment boundary)
    #pragma unroll
    for (int k = 0; k < RPT; ++k) {
        int ly = ty * RPT + k;
        const float* rowp = prob + (long)(y0 + ly) * W + x0;
        bool f0 = rowp[lx] > 0.5f;
        bool f1 = rowp[64 + lx] > 0.5f;
        unsigned long long m0 = __ballot(f0);
        unsigned long long m1 = __ballot(f1);
        rM0[k] = m0; rM1[k] = m1;
        int s0 = f0 ? run_start128(m0, m1, lx) : lx;
        int s1 = f1 ? run_start128(m0, m1, 64 + lx) : 64 + lx;
        sA[k] = s0; sB[k] = s1;
        slab[ly * TSX + lx]      = f0 ? ly * TSX + s0 : -1;
        slab[ly * TSX + 64 + lx] = f1 ? ly * TSX + s1 : -1;
        if (lx == 0) { mrow0[ly] = m0; mrow1[ly] = m1; }
    }
    __syncthreads();

    // vertical unions, once per (my-run, upper-segment) overlap.
    // Control uses ONLY register-cached / mask-table values (slab roots
    // mutate under concurrent lunite -- round-4 lesson).
    #pragma unroll
    for (int k = 0; k < RPT; ++k) {
        int ly = ty * RPT + k;
        if (ly == 0) continue;
        unsigned long long u0 = mrow0[ly - 1], u1 = mrow1[ly - 1];
        unsigned long long m0 = rM0[k], m1 = rM1[k];
        #pragma unroll
        for (int h = 0; h < 2; ++h) {
            int pos = h * 64 + lx;
            if (!getbit128(m0, m1, pos)) continue;
            int s = h ? sB[k] : sA[k];
            int mylab = ly * TSX + s;
            if (getbit128(u0, u1, pos)) {
                if (pos == s || !getbit128(u0, u1, pos - 1))
                    lunite(slab, mylab, (ly - 1) * TSX + run_start128(u0, u1, pos));
            } else {
                if (pos == s && getbit128(u0, u1, pos - 1))
                    lunite(slab, mylab, (ly - 1) * TSX + run_start128(u0, u1, pos - 1));
                bool isEnd = (pos == 127) || !getbit128(m0, m1, pos + 1);
                if (isEnd && getbit128(u0, u1, pos + 1))
                    lunite(slab, mylab, (ly - 1) * TSX + (pos + 1));
            }
        }
    }
    __syncthreads();

    // flatten step a: pre-flatten RUN-START entries only. Tree is static
    // now; plain stores write true roots.
    #pragma unroll
    for (int k = 0; k < RPT; ++k) {
        int ly = ty * RPT + k;
        unsigned long long m0 = rM0[k], m1 = rM1[k];
        if (((m0 >> lx) & 1) && sA[k] == lx) {
            int li = ly * TSX + lx;
            slab[li] = lfind(slab, li);
        }
        if (((m1 >> lx) & 1) && sB[k] == 64 + lx) {
            int li = ly * TSX + 64 + lx;
            slab[li] = lfind(slab, li);
        }
    }
    __syncthreads();

    // flatten step b: one LDS read at the register-cached run start
    // (same-run lanes broadcast). Edge labels also go to the seam sidecar.
    #pragma unroll
    for (int k = 0; k < RPT; ++k) {
        int ly = ty * RPT + k;
        unsigned long long m0 = rM0[k], m1 = rM1[k];
        int out0 = 0, out1 = 0;
        if ((m0 >> lx) & 1) {
            int r = slab[ly * TSX + sA[k]];
            out0 = (y0 + (r >> 7)) * W + (x0 + (r & 127)) + 1;
        }
        if ((m1 >> lx) & 1) {
            int r = slab[ly * TSX + sB[k]];
            out1 = (y0 + (r >> 7)) * W + (x0 + (r & 127)) + 1;
        }
        lab[(long)(y0 + ly) * W + x0 + lx]      = out0;
        lab[(long)(y0 + ly) * W + x0 + 64 + lx] = out1;
        if (lx == 0 && blockIdx.x > 0)            // left edge -> B side
            wsv[(blockIdx.x - 1) * 4096 + 2048 + (y0 + ly)] = out0;
        if (lx == 63 && blockIdx.x < 15)          // right edge -> A side
            wsv[blockIdx.x * 4096 + (y0 + ly)] = out1;
    }
}

// Cross-tile seam merge. 736 wave-tasks: 240 vertical (sidecar) + 496
// horizontal (contiguous lab rows). One gunite per (B-run, A-run) overlap
// segment (covered / left-touch / right-touch). Chunks crossing
// perpendicular tile boundaries stay correct by transitivity.
__global__ __launch_bounds__(256)
void k_seam(int* __restrict__ lab, const int* __restrict__ wsv) {
    int gtid = blockIdx.x * blockDim.x + threadIdx.x;
    int task = gtid >> 6;
    int lane = gtid & 63;
    bool vertical = task < 240;
    int t = vertical ? task : task - 240;
    int seam = t >> 4, chunk = t & 15;

    const int* aPtr;
    const int* bPtr;
    int y_h = 0, xb_h = 0;
    if (vertical) {
        int ybase = chunk << 7;            // 128-row chunk
        aPtr = wsv + seam * 4096 + ybase;          // col x-1 labels
        bPtr = wsv + seam * 4096 + 2048 + ybase;   // col x   labels
    } else {
        y_h = (seam + 1) << 6;             // seam row (every 64)
        xb_h = chunk << 7;
        bPtr = lab + (long)y_h * W + xb_h;
        aPtr = bPtr - W;
    }
    int B0 = bPtr[lane], B1 = bPtr[64 + lane];
    int A0 = aPtr[lane], A1 = aPtr[64 + lane];

    unsigned long long m0 = __ballot(B0 != 0), m1 = __ballot(B1 != 0);
    unsigned long long u0 = __ballot(A0 != 0), u1 = __ballot(A1 != 0);

    #pragma unroll
    for (int h = 0; h < 2; ++h) {
        int pos = (h << 6) | lane;
        if (!getbit128(m0, m1, pos)) continue;
        int myB = h ? B1 : B0;
        int s = run_start128(m0, m1, pos);
        if (getbit128(u0, u1, pos)) {
            if (pos == s || !getbit128(u0, u1, pos - 1)) {
                int tgt = h ? A1 : A0;
                gunite(lab, myB - 1, tgt - 1);
            }
        } else {
            if (pos == s && pos > 0 && getbit128(u0, u1, pos - 1)) {
                gunite(lab, myB - 1, aPtr[pos - 1] - 1);
            }
            bool isEnd = (pos == 127) || !getbit128(m0, m1, pos + 1);
            if (isEnd && pos < 127 && getbit128(u0, u1, pos + 1)) {
                gunite(lab, myB - 1, aPtr[pos + 1] - 1);
            }
        }
    }

    // corner diagonal links (horizontal chunks only, edge lanes)
    if (!vertical && lane == 0) {
        if (xb_h > 0 && (m0 & 1) && !(u0 & 1)) {           // NW corner
            int tgt = lab[(long)(y_h - 1) * W + xb_h - 1];
            if (tgt) gunite(lab, B0 - 1, tgt - 1);
        }
        if (xb_h + 128 < W && ((m1 >> 63) & 1) && !((u1 >> 63) & 1)) {  // NE
            int tgt = lab[(long)(y_h - 1) * W + xb_h + 128];
            if (tgt) {
                int b127 = lab[(long)y_h * W + xb_h + 127];
                gunite(lab, b127 - 1, tgt - 1);
            }
        }
    }
}

// READ-ONLY compress, int4-vectorized: 4 px/thread with chase-sharing
// (consecutive labels usually identical -- same run). Tree is static here;
// no halving writes. Concurrent readers of our 16B store see old-or-new
// per 4B element, both valid ancestors.
__device__ __forceinline__ int resolve(const int* __restrict__ L, int v) {
    if (v == 0) return 0;
    int a = v - 1;
    int n = L[a];
    while (n != a + 1) { a = n - 1; n = L[a]; }
    return a + 1;
}

__global__ __launch_bounds__(256)
void k_compress(int* __restrict__ lab) {
    int q = blockIdx.x * blockDim.x + threadIdx.x;  // quad index
    int4 v = ((const int4*)lab)[q];
    int o0 = resolve(lab, v.x);
    int o1 = (v.y == v.x) ? o0 : resolve(lab, v.y);
    int o2 = (v.z == v.y) ? o1 : resolve(lab, v.z);
    int o3 = (v.w == v.z) ? o2 : resolve(lab, v.w);
    if (o0 != v.x || o1 != v.y || o2 != v.z || o3 != v.w)
        ((int4*)lab)[q] = make_int4(o0, o1, o2, o3);
}

extern "C" void kernel_launch(void* const* d_in, const int* in_sizes, int n_in,
                              void* d_out, int out_size, void* d_ws, size_t ws_size,
                              hipStream_t stream) {
    const float* prob = (const float*)d_in[0];
    int* lab = (int*)d_out;
    int* wsv = (int*)d_ws;               // 240 KB sidecar

    dim3 lgrid(W / TSX, H / TSY);        // 16 x 32 = 512 blocks (2/CU)
    dim3 lblock(64, 16);                 // 1024 threads, 16 waves
    k_local<<<lgrid, lblock, 0, stream>>>(prob, lab, wsv);

    // 736 wave-tasks * 64 lanes = 47104 threads = 184 blocks exactly
    k_seam<<<184, 256, 0, stream>>>(lab, wsv);

    k_compress<<<NPIX / 4 / 256, 256, 0, stream>>>(lab);
}

// Round 18
// 73.642 us; speedup vs baseline: 1.2178x; 1.0001x over previous
//
#include <hip/hip_runtime.h>

// 8-connected CCL on a 2048x2048 mask (prob > 0.5).
// Output int32: (component min flat index)+1 for fg, 0 for bg.
//
// ROUND-16 CONFIGURATION (measured best, 73.65 us). Family bracketing:
//   gunite = halving-find + attach, PLAIN L1 loads   -> ~30 us (r11/r14) BEST
//   gunite = halving-find + attach, agent-scope loads-> ~52 us (r8)
//   gunite = pure-read find + attach (no halving)    -> ~45 us (r15)
//   gunite = atomicMin walk (no find)                -> ~149 us (r9)
// Cooperative 3-phase fusion (r17) fails to launch under the harness.
// Lesson: wave latency ~ longest-chain hops x mem latency; halving bounds
// chain growth, plain loads keep hops in L1, attach-retry repairs staleness.
//
//   1. k_local   : per 128x64 tile (32KB LDS, 2 blocks/CU), ballot/run-based
//                  union-find (round-12 proven form -- NO seeded parents:
//                  seeding built deep chains, 3x regression r13).
//   2. k_seam    : cross-tile unions, 128-px chunks, run-dedup'd;
//                  vertical seams read a coalesced d_ws sidecar.
//   3. k_compress: READ-ONLY chase, int4-vectorized, chase-sharing.

#define H 2048
#define W 2048
#define NPIX (H * W)
#define TSX 128           // tile width  (mask = 2 x u64)
#define TSY 64            // tile height
#define RPT 4             // rows per thread = TSY / 16

// sidecar layout (int32 units): seam s in 0..14 at column x=128(s+1):
//   A side (col x-1): wsv[s*4096 + y]   B side (col x): wsv[s*4096+2048+y]
// 15*4096 ints = 240 KB; every slot rewritten every call (bg writes 0).

// ---------- global union-find, 1-based parents, path-halving find ----------
// PLAIN loads: L1 may serve stale parents. SAFE: stale parent = past
// ancestor (same component; parents only decrease); halving atomicMin only
// lowers toward a valid ancestor; stale roots are caught at attach (atomics
// coherent) and the failed-attach continuation repairs any severed link.
__device__ __forceinline__ int gfind(int* __restrict__ L, int a) {
    int n = L[a];
    while (n != a + 1) {
        int p = n - 1;
        int g = L[p];                     // grandparent+1 (possibly stale)
        if (g != n) atomicMin(&L[a], g);  // MUST be atomicMin (see above)
        a = p; n = g;
    }
    return a;
}

__device__ __forceinline__ void gunite(int* __restrict__ L, int a, int b) {
    while (true) {
        a = gfind(L, a);
        b = gfind(L, b);
        if (a == b) return;
        if (a > b) { int t = a; a = b; b = t; }
        int old = atomicMin(&L[b], a + 1);
        if (old == b + 1) return;   // attached larger root under smaller
        b = old - 1;                // raced/stale; continue from observed
    }                               // parent (repairs any severed link)
}

// ---------- local (LDS) union-find, 0-based, -1 = background ----------
__device__ __forceinline__ int lfind(volatile int* L, int a) {
    int n = L[a];
    while (n != a) { a = n; n = L[a]; }
    return a;
}

// find with atomicMin path-halving (safe under concurrent unions: parents
// only decrease and remain in-component)
__device__ __forceinline__ int lfind_h(int* L, int a) {
    volatile int* Lv = L;
    int n = Lv[a];
    while (n != a) {
        int g = Lv[n];
        if (g != n) atomicMin(&L[a], g);
        a = n; n = g;
    }
    return a;
}

__device__ __forceinline__ void lunite(int* L, int a, int b) {
    while (true) {
        a = lfind_h(L, a);
        b = lfind_h(L, b);
        if (a == b) return;
        if (a > b) { int t = a; a = b; b = t; }
        int old = atomicMin(&L[b], a);
        if (old == b) return;
        b = old;
    }
}

// run start (smallest s<=p with bits s..p all set; requires bit p set)
__device__ __forceinline__ int run_start64(unsigned long long m, int p) {
    if (p == 0) return 0;
    unsigned long long below = m << (64 - p);   // bit p-1 -> bit 63
    return p - __builtin_clzll(~below);         // minus count of leading ones
}

__device__ __forceinline__ int run_start128(unsigned long long u0,
                                            unsigned long long u1, int p) {
    if (p >= 64) {
        int s = run_start64(u1, p - 64) + 64;
        if (s == 64 && (u0 >> 63)) s = run_start64(u0, 63);  // continues left
        return s;
    }
    return run_start64(u0, p);
}

__device__ __forceinline__ int getbit128(unsigned long long u0,
                                         unsigned long long u1, int p) {
    if (p < 0 || p > 127) return 0;
    return (int)((p < 64 ? (u0 >> p) : (u1 >> (p - 64))) & 1ull);
}

__global__ __launch_bounds__(1024)
void k_local(const float* __restrict__ prob, int* __restrict__ lab,
             int* __restrict__ wsv) {
    __shared__ int slab[TSY * TSX];                       // 32 KB
    __shared__ unsigned long long mrow0[TSY], mrow1[TSY]; // 1 KB mask table
    const int x0 = blockIdx.x * TSX, y0 = blockIdx.y * TSY;
    const int lx = threadIdx.x;                 // 0..63 == lane
    const int ty = threadIdx.y;                 // 0..15

    unsigned long long rM0[RPT], rM1[RPT];
    int sA[RPT], sB[RPT];                       // run starts, register-cached

    // init: two ballots per row; label := row-global run start (kills all
    // horizontal unions, incl. across the 64-lane segment boundary)
    #pragma unroll
    for (int k = 0; k < RPT; ++k) {
        int ly = ty * RPT + k;
        const float* rowp = prob + (long)(y0 + ly) * W + x0;
        bool f0 = rowp[lx] > 0.5f;
        bool f1 = rowp[64 + lx] > 0.5f;
        unsigned long long m0 = __ballot(f0);
        unsigned long long m1 = __ballot(f1);
        rM0[k] = m0; rM1[k] = m1;
        int s0 = f0 ? run_start128(m0, m1, lx) : lx;
        int s1 = f1 ? run_start128(m0, m1, 64 + lx) : 64 + lx;
        sA[k] = s0; sB[k] = s1;
        slab[ly * TSX + lx]      = f0 ? ly * TSX + s0 : -1;
        slab[ly * TSX + 64 + lx] = f1 ? ly * TSX + s1 : -1;
        if (lx == 0) { mrow0[ly] = m0; mrow1[ly] = m1; }
    }
    __syncthreads();

    // vertical unions, once per (my-run, upper-segment) overlap.
    // Control uses ONLY register-cached / mask-table values (slab roots
    // mutate under concurrent lunite -- round-4 lesson).
    #pragma unroll
    for (int k = 0; k < RPT; ++k) {
        int ly = ty * RPT + k;
        if (ly == 0) continue;
        unsigned long long u0 = mrow0[ly - 1], u1 = mrow1[ly - 1];
        unsigned long long m0 = rM0[k], m1 = rM1[k];
        #pragma unroll
        for (int h = 0; h < 2; ++h) {
            int pos = h * 64 + lx;
            if (!getbit128(m0, m1, pos)) continue;
            int s = h ? sB[k] : sA[k];
            int mylab = ly * TSX + s;
            if (getbit128(u0, u1, pos)) {
                if (pos == s || !getbit128(u0, u1, pos - 1))
                    lunite(slab, mylab, (ly - 1) * TSX + run_start128(u0, u1, pos));
            } else {
                if (pos == s && getbit128(u0, u1, pos - 1))
                    lunite(slab, mylab, (ly - 1) * TSX + run_start128(u0, u1, pos - 1));
                bool isEnd = (pos == 127) || !getbit128(m0, m1, pos + 1);
                if (isEnd && getbit128(u0, u1, pos + 1))
                    lunite(slab, mylab, (ly - 1) * TSX + (pos + 1));
            }
        }
    }
    __syncthreads();

    // flatten step a: pre-flatten RUN-START entries only. Tree is static
    // now; plain stores write true roots.
    #pragma unroll
    for (int k = 0; k < RPT; ++k) {
        int ly = ty * RPT + k;
        unsigned long long m0 = rM0[k], m1 = rM1[k];
        if (((m0 >> lx) & 1) && sA[k] == lx) {
            int li = ly * TSX + lx;
            slab[li] = lfind(slab, li);
        }
        if (((m1 >> lx) & 1) && sB[k] == 64 + lx) {
            int li = ly * TSX + 64 + lx;
            slab[li] = lfind(slab, li);
        }
    }
    __syncthreads();

    // flatten step b: one LDS read at the register-cached run start
    // (same-run lanes broadcast). Edge labels also go to the seam sidecar.
    #pragma unroll
    for (int k = 0; k < RPT; ++k) {
        int ly = ty * RPT + k;
        unsigned long long m0 = rM0[k], m1 = rM1[k];
        int out0 = 0, out1 = 0;
        if ((m0 >> lx) & 1) {
            int r = slab[ly * TSX + sA[k]];
            out0 = (y0 + (r >> 7)) * W + (x0 + (r & 127)) + 1;
        }
        if ((m1 >> lx) & 1) {
            int r = slab[ly * TSX + sB[k]];
            out1 = (y0 + (r >> 7)) * W + (x0 + (r & 127)) + 1;
        }
        lab[(long)(y0 + ly) * W + x0 + lx]      = out0;
        lab[(long)(y0 + ly) * W + x0 + 64 + lx] = out1;
        if (lx == 0 && blockIdx.x > 0)            // left edge -> B side
            wsv[(blockIdx.x - 1) * 4096 + 2048 + (y0 + ly)] = out0;
        if (lx == 63 && blockIdx.x < 15)          // right edge -> A side
            wsv[blockIdx.x * 4096 + (y0 + ly)] = out1;
    }
}

// Cross-tile seam merge. 736 wave-tasks: 240 vertical (sidecar) + 496
// horizontal (contiguous lab rows). One gunite per (B-run, A-run) overlap
// segment (covered / left-touch / right-touch). Chunks crossing
// perpendicular tile boundaries stay correct by transitivity.
__global__ __launch_bounds__(256)
void k_seam(int* __restrict__ lab, const int* __restrict__ wsv) {
    int gtid = blockIdx.x * blockDim.x + threadIdx.x;
    int task = gtid >> 6;
    int lane = gtid & 63;
    bool vertical = task < 240;
    int t = vertical ? task : task - 240;
    int seam = t >> 4, chunk = t & 15;

    const int* aPtr;
    const int* bPtr;
    int y_h = 0, xb_h = 0;
    if (vertical) {
        int ybase = chunk << 7;            // 128-row chunk
        aPtr = wsv + seam * 4096 + ybase;          // col x-1 labels
        bPtr = wsv + seam * 4096 + 2048 + ybase;   // col x   labels
    } else {
        y_h = (seam + 1) << 6;             // seam row (every 64)
        xb_h = chunk << 7;
        bPtr = lab + (long)y_h * W + xb_h;
        aPtr = bPtr - W;
    }
    int B0 = bPtr[lane], B1 = bPtr[64 + lane];
    int A0 = aPtr[lane], A1 = aPtr[64 + lane];

    unsigned long long m0 = __ballot(B0 != 0), m1 = __ballot(B1 != 0);
    unsigned long long u0 = __ballot(A0 != 0), u1 = __ballot(A1 != 0);

    #pragma unroll
    for (int h = 0; h < 2; ++h) {
        int pos = (h << 6) | lane;
        if (!getbit128(m0, m1, pos)) continue;
        int myB = h ? B1 : B0;
        int s = run_start128(m0, m1, pos);
        if (getbit128(u0, u1, pos)) {
            if (pos == s || !getbit128(u0, u1, pos - 1)) {
                int tgt = h ? A1 : A0;
                gunite(lab, myB - 1, tgt - 1);
            }
        } else {
            if (pos == s && pos > 0 && getbit128(u0, u1, pos - 1)) {
                gunite(lab, myB - 1, aPtr[pos - 1] - 1);
            }
            bool isEnd = (pos == 127) || !getbit128(m0, m1, pos + 1);
            if (isEnd && pos < 127 && getbit128(u0, u1, pos + 1)) {
                gunite(lab, myB - 1, aPtr[pos + 1] - 1);
            }
        }
    }

    // corner diagonal links (horizontal chunks only, edge lanes)
    if (!vertical && lane == 0) {
        if (xb_h > 0 && (m0 & 1) && !(u0 & 1)) {           // NW corner
            int tgt = lab[(long)(y_h - 1) * W + xb_h - 1];
            if (tgt) gunite(lab, B0 - 1, tgt - 1);
        }
        if (xb_h + 128 < W && ((m1 >> 63) & 1) && !((u1 >> 63) & 1)) {  // NE
            int tgt = lab[(long)(y_h - 1) * W + xb_h + 128];
            if (tgt) {
                int b127 = lab[(long)y_h * W + xb_h + 127];
                gunite(lab, b127 - 1, tgt - 1);
            }
        }
    }
}

// READ-ONLY compress, int4-vectorized: 4 px/thread with chase-sharing
// (consecutive labels usually identical -- same run). Tree is static here;
// no halving writes. Concurrent readers of our 16B store see old-or-new
// per 4B element, both valid ancestors.
__device__ __forceinline__ int resolve(const int* __restrict__ L, int v) {
    if (v == 0) return 0;
    int a = v - 1;
    int n = L[a];
    while (n != a + 1) { a = n - 1; n = L[a]; }
    return a + 1;
}

__global__ __launch_bounds__(256)
void k_compress(int* __restrict__ lab) {
    int q = blockIdx.x * blockDim.x + threadIdx.x;  // quad index
    int4 v = ((const int4*)lab)[q];
    int o0 = resolve(lab, v.x);
    int o1 = (v.y == v.x) ? o0 : resolve(lab, v.y);
    int o2 = (v.z == v.y) ? o1 : resolve(lab, v.z);
    int o3 = (v.w == v.z) ? o2 : resolve(lab, v.w);
    if (o0 != v.x || o1 != v.y || o2 != v.z || o3 != v.w)
        ((int4*)lab)[q] = make_int4(o0, o1, o2, o3);
}

extern "C" void kernel_launch(void* const* d_in, const int* in_sizes, int n_in,
                              void* d_out, int out_size, void* d_ws, size_t ws_size,
                              hipStream_t stream) {
    const float* prob = (const float*)d_in[0];
    int* lab = (int*)d_out;
    int* wsv = (int*)d_ws;               // 240 KB sidecar

    dim3 lgrid(W / TSX, H / TSY);        // 16 x 32 = 512 blocks (2/CU)
    dim3 lblock(64, 16);                 // 1024 threads, 16 waves
    k_local<<<lgrid, lblock, 0, stream>>>(prob, lab, wsv);

    // 736 wave-tasks * 64 lanes = 47104 threads = 184 blocks exactly
    k_seam<<<184, 256, 0, stream>>>(lab, wsv);

    k_compress<<<NPIX / 4 / 256, 256, 0, stream>>>(lab);
}